// Round 6
// baseline (777.078 us; speedup 1.0000x reference)
//
#include <hip/hip_runtime.h>
#include <math.h>

#define BB  256
#define TT  2048
#define VV  64
#define DD  50
#define HH  50
#define HIDN 100

// [tok][j] = seqFMA_d(embed[tok][d]*Wx[d][j]) + b_rnn[j]; cols 50..63 = 0.
__device__ float g_emWxb[VV * 64];

// ---------------------------------------------------------------------------
// XLA/Eigen fast-tanh, FMA-CONTRACTED Horner (what XLA CPU emits on x86 with
// fp-contraction on): p/q rational, clamp +-7.90531110763549805, |x|<4e-4 -> x.
// fmaf == vfmadd231ss bitwise; f32 '/' is IEEE correctly-rounded on gfx950
// (no fast-math) == divss bitwise.
// ---------------------------------------------------------------------------
__device__ __forceinline__ float xla_tanhf_fma(float x) {
#pragma clang fp contract(off)
  float ax = fabsf(x);
  float cx = fminf(fmaxf(x, -7.90531110763549805f), 7.90531110763549805f);
  float x2 = cx * cx;                       // plain mul (not contractible)
  float p = -2.76076847742355e-16f;
  p = fmaf(x2, p, 2.00018790482477e-13f);
  p = fmaf(x2, p, -8.60467152213735e-11f);
  p = fmaf(x2, p, 5.12229709037114e-08f);
  p = fmaf(x2, p, 1.48572235717979e-05f);
  p = fmaf(x2, p, 6.37261928875436e-04f);
  p = fmaf(x2, p, 4.89352455891786e-03f);
  p = cx * p;                               // plain mul
  float q = 1.19825839466702e-06f;
  q = fmaf(x2, q, 1.18534705686654e-04f);
  q = fmaf(x2, q, 2.26843463243900e-03f);
  q = fmaf(x2, q, 4.89352518554385e-03f);
  float r = p / q;                          // IEEE f32 divide
  return (ax < 0.0004f) ? x : r;
}

// ---------------------------------------------------------------------------
// K1: xp table, Eigen-gemm bit-emulation: sequential ascending-d FMA chain,
// single accumulator from 0, then + b_rnn (separate elementwise add).
// ---------------------------------------------------------------------------
__global__ __launch_bounds__(256) void prep_kernel(
    const float* __restrict__ embed, const float* __restrict__ Wx,
    const float* __restrict__ b_rnn) {
#pragma clang fp contract(off)
  int o = blockIdx.x * 256 + threadIdx.x;
  if (o >= VV * 64) return;
  int v = o >> 6, j = o & 63;
  float val = 0.f;
  if (j < HH) {
    float s = 0.f;
    for (int d = 0; d < DD; ++d)
      s = fmaf(embed[v * DD + d], Wx[d * HH + j], s);   // seq-k FMA, ascending
    val = s + b_rnn[j];
  }
  g_emWxb[o] = val;
}

// ---------------------------------------------------------------------------
// K2: recurrence, bit-emulating the XLA-CPU-f32 step:
//   dot_j = seqFMA_{i<50}(h[i]*Wh[i][j]);  pre = xp_j + dot_j;
//   h = fast_tanh_contracted(pre)
// One wave per batch row; lane j owns Wh column j; h broadcast via LDS.
// Chaos math (R2-R6): amplification ~1.3e7 over T=2048 -> ANY reordering or
// ulp-off tanh => absmax 0.8-1.5 vs threshold 0.075. Order is load-bearing.
// ---------------------------------------------------------------------------
__global__ __launch_bounds__(64) void rnn_kernel(
    const int* __restrict__ inputs, const float* __restrict__ Wh,
    float* hs) {
#pragma clang fp contract(off)
  const int b = blockIdx.x;
  const int j = threadIdx.x;

  __shared__ __align__(16) float emw[VV * 64];  // 16 KB
  __shared__ int toks[TT];                      // 8 KB
  __shared__ __align__(16) float hbuf[64];

  for (int o = j; o < VV * 64; o += 64) emw[o] = g_emWxb[o];
  const int* row = inputs + (size_t)b * TT;
  for (int t = j; t < TT; t += 64) toks[t] = row[t];

  float whcol[HH];
#pragma unroll
  for (int i = 0; i < HH; ++i)
    whcol[i] = (j < HH) ? Wh[i * HH + j] : 0.f;

  hbuf[j] = 0.f;
  __syncthreads();

  float* outp = hs + (size_t)b * TT * 64;
  float xp = emw[toks[0] * 64 + j];

  for (int t = 0; t < TT; ++t) {
    float hreg[52];
    const float4* hp = reinterpret_cast<const float4*>(hbuf);
#pragma unroll
    for (int q = 0; q < 13; ++q) {      // 52 >= 50 values
      float4 hv = hp[q];                // uniform address -> LDS broadcast
      hreg[4 * q + 0] = hv.x;
      hreg[4 * q + 1] = hv.y;
      hreg[4 * q + 2] = hv.z;
      hreg[4 * q + 3] = hv.w;
    }

    float acc = 0.f;
#pragma unroll
    for (int i = 0; i < HH; ++i)
      acc = fmaf(hreg[i], whcol[i], acc);   // ascending i, single accumulator
    float pre = xp + acc;

    // prefetch next xp (independent of hbuf)
    int tn = toks[(t + 1 < TT) ? (t + 1) : (TT - 1)];
    float xpn = emw[tn * 64 + j];

    float h = xla_tanhf_fma(pre);
    outp[(size_t)t * 64 + j] = h;    // coalesced; cols 50..63 stay 0

    __syncthreads();  // all lanes done reading hbuf
    hbuf[j] = h;
    __syncthreads();  // h published
    xp = xpn;
  }
}

// ---------------------------------------------------------------------------
// K3: MLP head, one THREAD per (b,t) row, f32 (non-amplified; ~1e-5 order
// tolerance). Weights at uniform addresses -> scalar loads. hs/out may alias
// (in-place fallback) -> NO restrict.
// ---------------------------------------------------------------------------
__global__ __launch_bounds__(256) void head_kernel(
    const float* hs, const float* __restrict__ W1,
    const float* __restrict__ b1, const float* __restrict__ W2,
    const float* __restrict__ b2, float* out) {
#pragma clang fp contract(off)
  const int r = blockIdx.x * 256 + threadIdx.x;  // 0 .. B*T-1
  const float* hrow = hs + (size_t)r * 64;

  float h[HH];
#pragma unroll
  for (int i = 0; i < HH; ++i) h[i] = hrow[i];

  float logit[VV];
#pragma unroll
  for (int jj = 0; jj < VV; ++jj) logit[jj] = b2[jj];

  for (int c = 0; c < HIDN; ++c) {
    float acc = 0.f;
#pragma unroll
    for (int i = 0; i < HH; ++i) acc = fmaf(h[i], W1[i * HIDN + c], acc);
    acc += b1[c];
    acc = fmaxf(acc, 0.f);
    const float* w2r = W2 + c * VV;
#pragma unroll
    for (int jj = 0; jj < VV; ++jj) logit[jj] = fmaf(acc, w2r[jj], logit[jj]);
  }

  float* orow = out + (size_t)r * 64;
#pragma unroll
  for (int jj = 0; jj < VV; ++jj) orow[jj] = logit[jj];
}

// ---------------------------------------------------------------------------
extern "C" void kernel_launch(void* const* d_in, const int* in_sizes, int n_in,
                              void* d_out, int out_size, void* d_ws, size_t ws_size,
                              hipStream_t stream) {
  // Map inputs by element-count signature (dict order breaks the Wx/Wh tie).
  const void* p[9] = {nullptr};
  const int want[9] = {BB * TT, VV * DD, DD * HH, HH * HH, HH,
                       HH * HIDN, HIDN, HIDN * VV, VV};
  bool used[32] = {false};
  for (int k = 0; k < 9; ++k)
    for (int i = 0; i < n_in && i < 32; ++i)
      if (!used[i] && in_sizes[i] == want[k]) { p[k] = d_in[i]; used[i] = true; break; }

  const int*   inputs = (const int*)  p[0];
  const float* embed  = (const float*)p[1];
  const float* Wx     = (const float*)p[2];
  const float* Wh     = (const float*)p[3];
  const float* b_rnn  = (const float*)p[4];
  const float* W1     = (const float*)p[5];
  const float* b1     = (const float*)p[6];
  const float* W2     = (const float*)p[7];
  const float* b2     = (const float*)p[8];

  float* out = (float*)d_out;
  float* hs = (ws_size >= (size_t)(BB * TT * 64) * sizeof(float))
                  ? (float*)d_ws : out;

  prep_kernel<<<(VV * 64 + 255) / 256, 256, 0, stream>>>(embed, Wx, b_rnn);
  rnn_kernel<<<BB, 64, 0, stream>>>(inputs, Wh, hs);
  head_kernel<<<(BB * TT) / 256, 256, 0, stream>>>(hs, W1, b1, W2, b2, out);
}